// Round 5
// baseline (331.346 us; speedup 1.0000x reference)
//
#include <hip/hip_runtime.h>

// Problem: B=2048, H=4, D=4096, M=8, dm=512.
// s_flat[r,j] = sum_h x[b,h,m*512+c]*lW[m,h] + lb[m],
//   m=r>>8, b=(r&255)*8+(j>>9), c=j&511.
// out[r,n] = sigmoid(sum_j s_flat[r,j]*pW[n,j] + pb[n]),  out fp32 [2048][4096].
//
// R9: prep unchanged (R8/R0-exact). GEMM ported from the m97 2-barrier
// structure (ceiling ~850-900 TF, documented closed) to the m201-style
// counted-vmcnt phase schedule (T3+T4+T5):
//   BM=128 BN=256 BK=64, 512 thr (8 waves 2x4), grid 16x16 = 256 blocks
//   (1/CU; 256-sq tile would leave half the CUs idle at M=2048).
//   3 tile-buffers (144 KiB LDS), depth-2 prefetch, vmcnt(6) at tile
//   boundaries (never 0 in the main loop), raw s_barrier + asm waitcnt
//   (no __syncthreads -> no compiler vmcnt(0) drain), setprio around MFMA.
// LDS swizzle + fragment math byte-identical to the proven R0 kernel.

#define MD 2048
#define ND 4096
#define KD 4096

typedef __attribute__((ext_vector_type(8))) __bf16 bf16x8;
typedef __attribute__((ext_vector_type(4))) float f32x4;

static __device__ __forceinline__ unsigned short f2bf(float f) {
  union { float f; unsigned int u; } v; v.f = f;
  unsigned int u = v.u;
  u += 0x7FFFu + ((u >> 16) & 1u);   // RNE
  return (unsigned short)(u >> 16);
}

// Prep (R0-exact): one-shot threads, 8x16B loads in flight, plain cacheable
// loads, 16B stores.
// blocks [0,4096): s_flat (bf16), 8 j's per thread.
// blocks [4096,8192): proj_W fp32 -> bf16, 16 floats per thread.
__global__ __launch_bounds__(256) void prep_kernel(
    const float* __restrict__ x, const float* __restrict__ lW,
    const float* __restrict__ lb, const float* __restrict__ pW,
    unsigned short* __restrict__ sB, unsigned short* __restrict__ wB) {
  int bid = blockIdx.x;
  int tid = threadIdx.x;
  if (bid < 4096) {
    int g = bid * 256 + tid;                  // 0 .. 2^20
    int j8 = g << 3;                          // flat index r*4096 + j, j8 % 8 == 0
    int r = j8 >> 12;
    int j = j8 & 4095;
    int m = r >> 8;
    int b = ((r & 255) << 3) + (j >> 9);
    int c = j & 511;                          // 8 consecutive j stay in one 512-group
    const float* xp = x + ((long)b << 14) + m * 512 + c;
    float w0 = lW[m * 4 + 0], w1 = lW[m * 4 + 1], w2 = lW[m * 4 + 2], w3 = lW[m * 4 + 3];
    float bb = lb[m];
    float4 xa0 = *(const float4*)(xp);
    float4 xb0 = *(const float4*)(xp + 4);
    float4 xa1 = *(const float4*)(xp + 4096);
    float4 xb1 = *(const float4*)(xp + 4100);
    float4 xa2 = *(const float4*)(xp + 8192);
    float4 xb2 = *(const float4*)(xp + 8196);
    float4 xa3 = *(const float4*)(xp + 12288);
    float4 xb3 = *(const float4*)(xp + 12292);
    float v0 = bb + xa0.x * w0 + xa1.x * w1 + xa2.x * w2 + xa3.x * w3;
    float v1 = bb + xa0.y * w0 + xa1.y * w1 + xa2.y * w2 + xa3.y * w3;
    float v2 = bb + xa0.z * w0 + xa1.z * w1 + xa2.z * w2 + xa3.z * w3;
    float v3 = bb + xa0.w * w0 + xa1.w * w1 + xa2.w * w2 + xa3.w * w3;
    float v4 = bb + xb0.x * w0 + xb1.x * w1 + xb2.x * w2 + xb3.x * w3;
    float v5 = bb + xb0.y * w0 + xb1.y * w1 + xb2.y * w2 + xb3.y * w3;
    float v6 = bb + xb0.z * w0 + xb1.z * w1 + xb2.z * w2 + xb3.z * w3;
    float v7 = bb + xb0.w * w0 + xb1.w * w1 + xb2.w * w2 + xb3.w * w3;
    uint4 pk;
    pk.x = (unsigned)f2bf(v0) | ((unsigned)f2bf(v1) << 16);
    pk.y = (unsigned)f2bf(v2) | ((unsigned)f2bf(v3) << 16);
    pk.z = (unsigned)f2bf(v4) | ((unsigned)f2bf(v5) << 16);
    pk.w = (unsigned)f2bf(v6) | ((unsigned)f2bf(v7) << 16);
    *(uint4*)(sB + j8) = pk;                  // 16B store
  } else {
    int g = (bid - 4096) * 256 + tid;         // 0 .. 2^20, x16 floats
    long off = (long)g << 4;
    float4 a = *(const float4*)(pW + off);
    float4 b4 = *(const float4*)(pW + off + 4);
    float4 c4 = *(const float4*)(pW + off + 8);
    float4 d4 = *(const float4*)(pW + off + 12);
    uint4 p0, p1;
    p0.x = (unsigned)f2bf(a.x) | ((unsigned)f2bf(a.y) << 16);
    p0.y = (unsigned)f2bf(a.z) | ((unsigned)f2bf(a.w) << 16);
    p0.z = (unsigned)f2bf(b4.x) | ((unsigned)f2bf(b4.y) << 16);
    p0.w = (unsigned)f2bf(b4.z) | ((unsigned)f2bf(b4.w) << 16);
    p1.x = (unsigned)f2bf(c4.x) | ((unsigned)f2bf(c4.y) << 16);
    p1.y = (unsigned)f2bf(c4.z) | ((unsigned)f2bf(c4.w) << 16);
    p1.z = (unsigned)f2bf(d4.x) | ((unsigned)f2bf(d4.y) << 16);
    p1.w = (unsigned)f2bf(d4.z) | ((unsigned)f2bf(d4.w) << 16);
    *(uint4*)(wB + off) = p0;
    *(uint4*)(wB + off + 8) = p1;
  }
}

// GEMM: C[2048][4096] = S[2048][4096] * W[4096][4096]^T (both bf16, K
// contiguous), epilogue sigmoid(acc + pb[n]) -> fp32.
// Counted-vmcnt phase schedule (m201 recipe): per K-tile 2 phases of
// {8x ds_read_b128 ; [phase0: stage tile t+2] ; s_barrier ; lgkmcnt(0) ;
//  setprio(1) ; 16 MFMA ; setprio(0) ; s_barrier}, and ONE
// vmcnt(6)+s_barrier per tile boundary (depth-2 prefetch stays in flight).
//
// Safety: buffer (t+2)%3 staged at iter-t phase0 was last ds_read at
// iter t-1 phase1; every wave's lgkmcnt(0) precedes the end-of-iter barrier,
// so no overwrite-before-read-complete. Tile t+1 readiness = vmcnt(6)
// (12 outstanding - 6 newest) + barrier. Prologue stages {0,1}; iter t
// stages t+2 -> tiles 0..63 staged exactly once.
#define BM 128
#define BN 256
#define BK 64
#define NT (KD / BK)   // 64

__global__ __launch_bounds__(512) void gemm_kernel(
    const unsigned short* __restrict__ S, const unsigned short* __restrict__ W,
    const float* __restrict__ pb, float* __restrict__ out) {
  __shared__ unsigned short As[3][BM * BK];   // 3 x 16 KiB
  __shared__ unsigned short Bs[3][BN * BK];   // 3 x 32 KiB  (total 144 KiB)
  int tid = threadIdx.x;
  int lane = tid & 63;
  int wave = tid >> 6;            // 0..7
  int n0 = blockIdx.x * BN;       // 16 n-tiles
  int r0 = blockIdx.y * BM;       // 16 m-tiles
  int wr = wave >> 2;             // 0..1  (64-row A panel)
  int wc = wave & 3;              // 0..3  (64-row B panel)

  // Staging: row = tid>>3 (+64 per issue), phys chunk = tid&7 holds global
  // chunk (tid&7) ^ (row&7)  [row&7 == (lane>>3)&7: wave*8 and i*64 are 0 mod 8].
  // LDS dest is wave-uniform base + lane*16B (linear [row][64] ushorts).
  int strow = tid >> 3;                                  // 0..63
  int sgoff = (((tid & 7) ^ ((tid >> 3) & 7)) << 3);     // pre-swizzled k offset
  const unsigned short* gA = S + (long)(r0 + strow) * KD + sgoff;
  const unsigned short* gB = W + (long)(n0 + strow) * KD + sgoff;

#define STAGE(pbuf, tt) do {                                                   \
    const long ko_ = (long)(tt) * BK;                                          \
    _Pragma("unroll")                                                          \
    for (int i_ = 0; i_ < 2; ++i_)                                             \
      __builtin_amdgcn_global_load_lds(                                        \
          (const __attribute__((address_space(1))) unsigned int*)(gA + (long)i_ * 64 * KD + ko_), \
          (__attribute__((address_space(3))) unsigned int*)(&As[pbuf][(i_ * 64 + (wave << 3)) * BK]), 16, 0, 0); \
    _Pragma("unroll")                                                          \
    for (int i_ = 0; i_ < 4; ++i_)                                             \
      __builtin_amdgcn_global_load_lds(                                        \
          (const __attribute__((address_space(1))) unsigned int*)(gB + (long)i_ * 64 * KD + ko_), \
          (__attribute__((address_space(3))) unsigned int*)(&Bs[pbuf][(i_ * 64 + (wave << 3)) * BK]), 16, 0, 0); \
  } while (0)

  // fragment reads: identical math to the proven kernel (0 bank conflicts)
#define LOADFRAG(pp, av, bv, ksv) do {                                         \
    int swz_ = ((((ksv) << 2) + (lane >> 4)) ^ (lane & 7)) << 3;               \
    _Pragma("unroll")                                                          \
    for (int t_ = 0; t_ < 4; ++t_) {                                           \
      av[t_] = *(const bf16x8*)&As[pp][((wr << 6) + t_ * 16 + (lane & 15)) * BK + swz_]; \
      bv[t_] = *(const bf16x8*)&Bs[pp][((wc << 6) + t_ * 16 + (lane & 15)) * BK + swz_]; \
    }                                                                          \
  } while (0)

#define MFMA16(av, bv) do {                                                    \
    _Pragma("unroll")                                                          \
    for (int mt_ = 0; mt_ < 4; ++mt_)                                          \
      _Pragma("unroll")                                                        \
      for (int nt_ = 0; nt_ < 4; ++nt_)                                        \
        acc[mt_][nt_] = __builtin_amdgcn_mfma_f32_16x16x32_bf16(               \
            av[mt_], bv[nt_], acc[mt_][nt_], 0, 0, 0);                         \
  } while (0)

  f32x4 acc[4][4] = {};

  // prologue: stage tiles 0,1 (12 loads); wait tile0 done (vmcnt(6)); publish
  STAGE(0, 0);
  STAGE(1, 1);
  asm volatile("s_waitcnt vmcnt(6)" ::: "memory");
  __builtin_amdgcn_s_barrier();

  for (int t = 0; t < NT; ++t) {
    const int p = t % 3;
    // ---------------- phase 0 (ks = 0) ----------------
    bf16x8 a0[4], b0[4];
    LOADFRAG(p, a0, b0, 0);
    if (t + 2 < NT) STAGE((t + 2) % 3, t + 2);   // buf last read at iter t-1; safe
    __builtin_amdgcn_s_barrier();
    asm volatile("s_waitcnt lgkmcnt(0)" ::: "memory");
    __builtin_amdgcn_s_setprio(1);
    MFMA16(a0, b0);
    __builtin_amdgcn_s_setprio(0);
    __builtin_amdgcn_s_barrier();
    // ---------------- phase 1 (ks = 1) ----------------
    bf16x8 a1[4], b1[4];
    LOADFRAG(p, a1, b1, 1);
    __builtin_amdgcn_s_barrier();
    asm volatile("s_waitcnt lgkmcnt(0)" ::: "memory");
    __builtin_amdgcn_s_setprio(1);
    MFMA16(a1, b1);
    __builtin_amdgcn_s_setprio(0);
    // -------- tile boundary: publish tile t+1, keep t+2 in flight --------
    if (t + 1 < NT) {
      if (t + 2 < NT) {
        asm volatile("s_waitcnt vmcnt(6)" ::: "memory");   // never 0 mid-loop (T4)
      } else {
        asm volatile("s_waitcnt vmcnt(0)" ::: "memory");   // drain last tile
      }
      __builtin_amdgcn_s_barrier();
    }
  }

  // epilogue: C/D layout col=lane&15, row=(lane>>4)*4+i  [m89/m91]
#pragma unroll
  for (int nt = 0; nt < 4; ++nt) {
    int col = n0 + (wc << 6) + nt * 16 + (lane & 15);
    float pbv = pb[col];
#pragma unroll
    for (int mt = 0; mt < 4; ++mt) {
      int row = r0 + (wr << 6) + mt * 16 + ((lane >> 4) << 2);
#pragma unroll
      for (int i = 0; i < 4; ++i) {
        float v = acc[mt][nt][i] + pbv;
        out[(long)(row + i) * ND + col] = 1.0f / (1.0f + __expf(-v));
      }
    }
  }
#undef STAGE
#undef LOADFRAG
#undef MFMA16
}

extern "C" void kernel_launch(void* const* d_in, const int* in_sizes, int n_in,
                              void* d_out, int out_size, void* d_ws, size_t ws_size,
                              hipStream_t stream) {
  const float* x  = (const float*)d_in[0];   // (2048, 4, 4096)
  const float* lW = (const float*)d_in[1];   // (8, 4)
  const float* lb = (const float*)d_in[2];   // (8,)
  const float* pW = (const float*)d_in[3];   // (4096, 4096)
  const float* pb = (const float*)d_in[4];   // (4096,)
  float* out = (float*)d_out;                // (2048, 4096) fp32

  unsigned short* sB = (unsigned short*)d_ws;          // 2048*4096 bf16 = 16 MiB
  unsigned short* wB = sB + (long)MD * KD;             // 4096*4096 bf16 = 32 MiB

  prep_kernel<<<8192, 256, 0, stream>>>(x, lW, lb, pW, sB, wB);
  gemm_kernel<<<dim3(16, 16), 512, 0, stream>>>(sB, wB, pb, out);
}

// Round 6
// 325.744 us; speedup vs baseline: 1.0172x; 1.0172x over previous
//
#include <hip/hip_runtime.h>

// Problem: B=2048, H=4, D=4096, M=8, dm=512.
// s_flat[r,j] = sum_h x[b,h,m*512+c]*lW[m,h] + lb[m],
//   m=r>>8, b=(r&255)*8+(j>>9), c=j&511.
// out[r,n] = sigmoid(sum_j s_flat[r,j]*pW[n,j] + pb[n]),  out fp32 [2048][4096].
//
// R10: gemm reverted to R8-exact (m97-structure + T1 swizzle; R9's counted-
// vmcnt port at 128x256 replicated the documented-null m232 quadrant: 87 us,
// MfmaUtil 31% -- 1 block/CU lockstep has no anti-phase cover).
// Prep v5: MLP doubling. s-path thread handles rows r AND r+1024 of the same
// j-block (same b, same c; x data at +2048 floats; weights m+4) -> 16
// independent 16B loads in flight (was 8). w-path: 32 floats/thread (8 loads,
// 4 stores; was 4/2). Mechanism test: prep at 2.76 TB/s logical with
// VALUBusy 4% / occ 70% looks outstanding-bytes-limited, not pipe-limited.

#define MD 2048
#define ND 4096
#define KD 4096

typedef __attribute__((ext_vector_type(8))) __bf16 bf16x8;
typedef __attribute__((ext_vector_type(4))) float f32x4;

static __device__ __forceinline__ unsigned short f2bf(float f) {
  union { float f; unsigned int u; } v; v.f = f;
  unsigned int u = v.u;
  u += 0x7FFFu + ((u >> 16) & 1u);   // RNE
  return (unsigned short)(u >> 16);
}

// Prep v5: blocks [0,2048): s_flat rows r and r+1024, 8 j's each (16 loads).
// blocks [2048,4096): proj_W fp32 -> bf16, 32 floats per thread (8 loads).
__global__ __launch_bounds__(256) void prep_kernel(
    const float* __restrict__ x, const float* __restrict__ lW,
    const float* __restrict__ lb, const float* __restrict__ pW,
    unsigned short* __restrict__ sB, unsigned short* __restrict__ wB) {
  int bid = blockIdx.x;
  int tid = threadIdx.x;
  if (bid < 2048) {
    int g = bid * 256 + tid;                  // 0 .. 2^19
    int j8 = g << 3;                          // r*4096 + j, r in [0,1024)
    int r = j8 >> 12;                         // 0..1023
    int j = j8 & 4095;
    int m = r >> 8;                           // 0..3  (row r+1024 -> m+4)
    int b = ((r & 255) << 3) + (j >> 9);      // same b for r and r+1024
    int c = j & 511;
    const float* xp = x + ((long)b << 14) + m * 512 + c;
    float w0 = lW[m * 4 + 0], w1 = lW[m * 4 + 1], w2 = lW[m * 4 + 2], w3 = lW[m * 4 + 3];
    float bb = lb[m];
    float u0 = lW[(m + 4) * 4 + 0], u1 = lW[(m + 4) * 4 + 1],
          u2 = lW[(m + 4) * 4 + 2], u3 = lW[(m + 4) * 4 + 3];
    float bb2 = lb[m + 4];
    // row r: 8 loads (strides of 4096 floats across h)
    float4 xa0 = *(const float4*)(xp);
    float4 xb0 = *(const float4*)(xp + 4);
    float4 xa1 = *(const float4*)(xp + 4096);
    float4 xb1 = *(const float4*)(xp + 4100);
    float4 xa2 = *(const float4*)(xp + 8192);
    float4 xb2 = *(const float4*)(xp + 8196);
    float4 xa3 = *(const float4*)(xp + 12288);
    float4 xb3 = *(const float4*)(xp + 12292);
    // row r+1024: same rows, +2048 floats (group m+4 within the same x[b,h,:])
    float4 ya0 = *(const float4*)(xp + 2048);
    float4 yb0 = *(const float4*)(xp + 2052);
    float4 ya1 = *(const float4*)(xp + 6144);
    float4 yb1 = *(const float4*)(xp + 6148);
    float4 ya2 = *(const float4*)(xp + 10240);
    float4 yb2 = *(const float4*)(xp + 10244);
    float4 ya3 = *(const float4*)(xp + 14336);
    float4 yb3 = *(const float4*)(xp + 14340);
    float v0 = bb + xa0.x * w0 + xa1.x * w1 + xa2.x * w2 + xa3.x * w3;
    float v1 = bb + xa0.y * w0 + xa1.y * w1 + xa2.y * w2 + xa3.y * w3;
    float v2 = bb + xa0.z * w0 + xa1.z * w1 + xa2.z * w2 + xa3.z * w3;
    float v3 = bb + xa0.w * w0 + xa1.w * w1 + xa2.w * w2 + xa3.w * w3;
    float v4 = bb + xb0.x * w0 + xb1.x * w1 + xb2.x * w2 + xb3.x * w3;
    float v5 = bb + xb0.y * w0 + xb1.y * w1 + xb2.y * w2 + xb3.y * w3;
    float v6 = bb + xb0.z * w0 + xb1.z * w1 + xb2.z * w2 + xb3.z * w3;
    float v7 = bb + xb0.w * w0 + xb1.w * w1 + xb2.w * w2 + xb3.w * w3;
    float z0 = bb2 + ya0.x * u0 + ya1.x * u1 + ya2.x * u2 + ya3.x * u3;
    float z1 = bb2 + ya0.y * u0 + ya1.y * u1 + ya2.y * u2 + ya3.y * u3;
    float z2 = bb2 + ya0.z * u0 + ya1.z * u1 + ya2.z * u2 + ya3.z * u3;
    float z3 = bb2 + ya0.w * u0 + ya1.w * u1 + ya2.w * u2 + ya3.w * u3;
    float z4 = bb2 + yb0.x * u0 + yb1.x * u1 + yb2.x * u2 + yb3.x * u3;
    float z5 = bb2 + yb0.y * u0 + yb1.y * u1 + yb2.y * u2 + yb3.y * u3;
    float z6 = bb2 + yb0.z * u0 + yb1.z * u1 + yb2.z * u2 + yb3.z * u3;
    float z7 = bb2 + yb0.w * u0 + yb1.w * u1 + yb2.w * u2 + yb3.w * u3;
    uint4 pk;
    pk.x = (unsigned)f2bf(v0) | ((unsigned)f2bf(v1) << 16);
    pk.y = (unsigned)f2bf(v2) | ((unsigned)f2bf(v3) << 16);
    pk.z = (unsigned)f2bf(v4) | ((unsigned)f2bf(v5) << 16);
    pk.w = (unsigned)f2bf(v6) | ((unsigned)f2bf(v7) << 16);
    *(uint4*)(sB + j8) = pk;                  // row r
    uint4 qk;
    qk.x = (unsigned)f2bf(z0) | ((unsigned)f2bf(z1) << 16);
    qk.y = (unsigned)f2bf(z2) | ((unsigned)f2bf(z3) << 16);
    qk.z = (unsigned)f2bf(z4) | ((unsigned)f2bf(z5) << 16);
    qk.w = (unsigned)f2bf(z6) | ((unsigned)f2bf(z7) << 16);
    *(uint4*)(sB + j8 + 4194304) = qk;        // row r+1024  (1024*4096)
  } else {
    int g = (bid - 2048) * 256 + tid;         // 0 .. 2^19, x32 floats
    long off = (long)g << 5;
    float4 a0 = *(const float4*)(pW + off);
    float4 a1 = *(const float4*)(pW + off + 4);
    float4 a2 = *(const float4*)(pW + off + 8);
    float4 a3 = *(const float4*)(pW + off + 12);
    float4 a4 = *(const float4*)(pW + off + 16);
    float4 a5 = *(const float4*)(pW + off + 20);
    float4 a6 = *(const float4*)(pW + off + 24);
    float4 a7 = *(const float4*)(pW + off + 28);
    uint4 p0, p1, p2, p3;
    p0.x = (unsigned)f2bf(a0.x) | ((unsigned)f2bf(a0.y) << 16);
    p0.y = (unsigned)f2bf(a0.z) | ((unsigned)f2bf(a0.w) << 16);
    p0.z = (unsigned)f2bf(a1.x) | ((unsigned)f2bf(a1.y) << 16);
    p0.w = (unsigned)f2bf(a1.z) | ((unsigned)f2bf(a1.w) << 16);
    p1.x = (unsigned)f2bf(a2.x) | ((unsigned)f2bf(a2.y) << 16);
    p1.y = (unsigned)f2bf(a2.z) | ((unsigned)f2bf(a2.w) << 16);
    p1.z = (unsigned)f2bf(a3.x) | ((unsigned)f2bf(a3.y) << 16);
    p1.w = (unsigned)f2bf(a3.z) | ((unsigned)f2bf(a3.w) << 16);
    p2.x = (unsigned)f2bf(a4.x) | ((unsigned)f2bf(a4.y) << 16);
    p2.y = (unsigned)f2bf(a4.z) | ((unsigned)f2bf(a4.w) << 16);
    p2.z = (unsigned)f2bf(a5.x) | ((unsigned)f2bf(a5.y) << 16);
    p2.w = (unsigned)f2bf(a5.z) | ((unsigned)f2bf(a5.w) << 16);
    p3.x = (unsigned)f2bf(a6.x) | ((unsigned)f2bf(a6.y) << 16);
    p3.y = (unsigned)f2bf(a6.z) | ((unsigned)f2bf(a6.w) << 16);
    p3.z = (unsigned)f2bf(a7.x) | ((unsigned)f2bf(a7.y) << 16);
    p3.w = (unsigned)f2bf(a7.z) | ((unsigned)f2bf(a7.w) << 16);
    *(uint4*)(wB + off) = p0;
    *(uint4*)(wB + off + 8) = p1;
    *(uint4*)(wB + off + 16) = p2;
    *(uint4*)(wB + off + 24) = p3;
  }
}

// m97-recipe GEMM (R8-exact): C[2048][4096] = S * W^T (both bf16, K
// contiguous), epilogue sigmoid(acc + pb[n]) -> fp32.
// 128x128 block tile, BK=64, 4 waves in 2x2, each wave 4x4 of 16x16x32 MFMA.
// LDS [row][64] ushorts with XOR 16B-chunk swizzle (phys = kc ^ (row&7)),
// filled by global_load_lds with the swizzle pre-applied to the per-lane
// GLOBAL source address (m173 pattern). Fragment reads: 0 bank conflicts.
// 32 KiB LDS, grid 512 -> 2 blocks/CU anti-phase cover (the structure's
// load-hiding mechanism; documented ceiling ~850-900 TF).
#define BM 128
#define BN 128
#define BK 64

__global__ __launch_bounds__(256) void gemm_kernel(
    const unsigned short* __restrict__ S, const unsigned short* __restrict__ W,
    const float* __restrict__ pb, float* __restrict__ out) {
  __shared__ unsigned short As[BM * BK];   // unpadded (global_load_lds)
  __shared__ unsigned short Bs[BN * BK];
  int tid = threadIdx.x;
  int lane = tid & 63;
  int wave = tid >> 6;

  // T1 XCD swizzle (neutral at L3-fit, kept from benched R8 artifact)
  int orig = blockIdx.x;                     // 0..511
  int wg = ((orig & 7) << 6) + (orig >> 3);
  int n0 = (wg & 31) * BN;                   // 32 n-tiles
  int r0 = (wg >> 5) * BM;                   // 16 m-tiles
  int wr = wave >> 1, wc = wave & 1;

  int srow = (wave << 5) + (lane >> 3);            // + i*8 per issue
  int scol = (((lane & 7) ^ (lane >> 3)) << 3);    // swizzled k-element offset
  const unsigned short* gA = S + (long)(r0 + srow) * KD + scol;
  const unsigned short* gB = W + (long)(n0 + srow) * KD + scol;
  unsigned short* lA = &As[(wave << 5) * BK];  // wave-uniform base; HW adds lane*16B
  unsigned short* lB = &Bs[(wave << 5) * BK];

  f32x4 acc[4][4] = {};

  for (int kt = 0; kt < KD; kt += BK) {
    __syncthreads();
#pragma unroll
    for (int i = 0; i < 4; ++i) {
      __builtin_amdgcn_global_load_lds(
          (const __attribute__((address_space(1))) unsigned int*)(gA + (long)i * 8 * KD + kt),
          (__attribute__((address_space(3))) unsigned int*)(lA + i * 8 * BK), 16, 0, 0);
      __builtin_amdgcn_global_load_lds(
          (const __attribute__((address_space(1))) unsigned int*)(gB + (long)i * 8 * KD + kt),
          (__attribute__((address_space(3))) unsigned int*)(lB + i * 8 * BK), 16, 0, 0);
    }
    __syncthreads();
#pragma unroll
    for (int ks = 0; ks < 2; ++ks) {
      // fragment chunk kc_lin = ks*4 + (lane>>4); physical chunk =
      // kc_lin ^ (row & 7); row&7 == lane&7 for all t (t*16 is 0 mod 8).
      int swz = (((ks << 2) + (lane >> 4)) ^ (lane & 7)) << 3;
      bf16x8 af[4], bfr[4];
#pragma unroll
      for (int t = 0; t < 4; ++t) {
        af[t]  = *(const bf16x8*)&As[((wr << 6) + t * 16 + (lane & 15)) * BK + swz];
        bfr[t] = *(const bf16x8*)&Bs[((wc << 6) + t * 16 + (lane & 15)) * BK + swz];
      }
#pragma unroll
      for (int mt = 0; mt < 4; ++mt)
#pragma unroll
        for (int nt = 0; nt < 4; ++nt)
          acc[mt][nt] = __builtin_amdgcn_mfma_f32_16x16x32_bf16(af[mt], bfr[nt], acc[mt][nt], 0, 0, 0);
    }
  }

  // epilogue: C/D layout col=lane&15, row=(lane>>4)*4+i  [m89/m91]
#pragma unroll
  for (int nt = 0; nt < 4; ++nt) {
    int col = n0 + (wc << 6) + nt * 16 + (lane & 15);
    float pbv = pb[col];
#pragma unroll
    for (int mt = 0; mt < 4; ++mt) {
      int row = r0 + (wr << 6) + mt * 16 + ((lane >> 4) << 2);
#pragma unroll
      for (int i = 0; i < 4; ++i) {
        float v = acc[mt][nt][i] + pbv;
        out[(long)(row + i) * ND + col] = 1.0f / (1.0f + __expf(-v));
      }
    }
  }
}

extern "C" void kernel_launch(void* const* d_in, const int* in_sizes, int n_in,
                              void* d_out, int out_size, void* d_ws, size_t ws_size,
                              hipStream_t stream) {
  const float* x  = (const float*)d_in[0];   // (2048, 4, 4096)
  const float* lW = (const float*)d_in[1];   // (8, 4)
  const float* lb = (const float*)d_in[2];   // (8,)
  const float* pW = (const float*)d_in[3];   // (4096, 4096)
  const float* pb = (const float*)d_in[4];   // (4096,)
  float* out = (float*)d_out;                // (2048, 4096) fp32

  unsigned short* sB = (unsigned short*)d_ws;          // 2048*4096 bf16 = 16 MiB
  unsigned short* wB = sB + (long)MD * KD;             // 4096*4096 bf16 = 32 MiB

  prep_kernel<<<4096, 256, 0, stream>>>(x, lW, lb, pW, sB, wB);
  gemm_kernel<<<512, 256, 0, stream>>>(sB, wB, pb, out);
}

// Round 7
// 323.385 us; speedup vs baseline: 1.0246x; 1.0073x over previous
//
#include <hip/hip_runtime.h>

// Problem: B=2048, H=4, D=4096, M=8, dm=512.
// s_flat[r,j] = sum_h x[b,h,m*512+c]*lW[m,h] + lb[m],
//   m=r>>8, b=(r&255)*8+(j>>9), c=j&511.
// out[r,n] = sigmoid(sum_j s_flat[r,j]*pW[n,j] + pb[n]),  out fp32 [2048][4096].
//
// R11: gemm = R8-exact (m97 structure + T1 swizzle; benched-good).
// Prep v6 -- DENSE-INSTRUCTION remap. v3's layout gave each thread 8-16
// CONSECUTIVE floats -> lane stride 32B/64B with 16B loads -> each vmem
// instruction touched its span at 50%/25% density = 2x/4x sector requests
// per useful byte. All prep variants (v3/v5/grid-stride) sat at the same
// 2.7-2.8 TB/s ~= 6.3/2.2 -- consistent with request-rate limiting, not
// byte-rate. v6: threads own STRIDED QUADS (4 floats), so every load is
// 64 lanes x 16B contiguous (1KB dense); stores are 8B wave-dense (512B).
// Same bytes, same FLOPs, bit-identical results.

#define MD 2048
#define ND 4096
#define KD 4096

typedef __attribute__((ext_vector_type(8))) __bf16 bf16x8;
typedef __attribute__((ext_vector_type(4))) float f32x4;

static __device__ __forceinline__ unsigned int f2bfu(float f) {
  union { float f; unsigned int u; } v; v.f = f;
  unsigned int u = v.u;
  u += 0x7FFFu + ((u >> 16) & 1u);   // RNE
  return u >> 16;
}
static __device__ __forceinline__ unsigned int pk2(float a, float b) {
  return f2bfu(a) | (f2bfu(b) << 16);
}

// Prep v6: blocks [0,4096): s_flat. Thread -> (r, bbi, c-quad t):
//   g = bid*256+tid; t = g&63; r = g>>9; bbi = (g>>6)&7.
//   Handles c = {4t..4t+3} and {256+4t..}; all 8 loads are wave-dense 1KB.
// blocks [4096,8192): proj_W fp32->bf16. Wave covers 4KB contiguous; thread
//   owns quads at +0/+256/+512/+768 floats; dense loads, 8B dense stores.
__global__ __launch_bounds__(256) void prep_kernel(
    const float* __restrict__ x, const float* __restrict__ lW,
    const float* __restrict__ lb, const float* __restrict__ pW,
    unsigned short* __restrict__ sB, unsigned short* __restrict__ wB) {
  int bid = blockIdx.x;
  int tid = threadIdx.x;
  if (bid < 4096) {
    int g = bid * 256 + tid;                  // 0 .. 2^20
    int t = g & 63;                           // c-quad index
    int gb = g >> 6;                          // (r, bbi) pair, 0..16383
    int r = gb >> 3;                          // 0..2047
    int bbi = gb & 7;                         // j >> 9
    int m = r >> 8;
    int b = ((r & 255) << 3) + bbi;
    int c0 = t << 2;
    const float* xp = x + ((long)b << 14) + m * 512 + c0;
    float w0 = lW[m * 4 + 0], w1 = lW[m * 4 + 1], w2 = lW[m * 4 + 2], w3 = lW[m * 4 + 3];
    float bb = lb[m];
    // 8 loads, each instruction dense: lanes t=0..63 cover 1KB contiguous
    float4 xa0 = *(const float4*)(xp);            // h=0, c0
    float4 xb0 = *(const float4*)(xp + 256);      // h=0, c0+256
    float4 xa1 = *(const float4*)(xp + 4096);     // h=1
    float4 xb1 = *(const float4*)(xp + 4352);
    float4 xa2 = *(const float4*)(xp + 8192);     // h=2
    float4 xb2 = *(const float4*)(xp + 8448);
    float4 xa3 = *(const float4*)(xp + 12288);    // h=3
    float4 xb3 = *(const float4*)(xp + 12544);
    float v0 = bb + xa0.x * w0 + xa1.x * w1 + xa2.x * w2 + xa3.x * w3;
    float v1 = bb + xa0.y * w0 + xa1.y * w1 + xa2.y * w2 + xa3.y * w3;
    float v2 = bb + xa0.z * w0 + xa1.z * w1 + xa2.z * w2 + xa3.z * w3;
    float v3 = bb + xa0.w * w0 + xa1.w * w1 + xa2.w * w2 + xa3.w * w3;
    float z0 = bb + xb0.x * w0 + xb1.x * w1 + xb2.x * w2 + xb3.x * w3;
    float z1 = bb + xb0.y * w0 + xb1.y * w1 + xb2.y * w2 + xb3.y * w3;
    float z2 = bb + xb0.z * w0 + xb1.z * w1 + xb2.z * w2 + xb3.z * w3;
    float z3 = bb + xb0.w * w0 + xb1.w * w1 + xb2.w * w2 + xb3.w * w3;
    long so = ((long)r << 12) + (bbi << 9) + c0;  // r*4096 + j
    uint2 pa, pbq;
    pa.x = pk2(v0, v1);  pa.y = pk2(v2, v3);
    pbq.x = pk2(z0, z1); pbq.y = pk2(z2, z3);
    *(uint2*)(sB + so) = pa;                  // 8B store, wave-dense 512B
    *(uint2*)(sB + so + 256) = pbq;
  } else {
    int g = (bid - 4096) * 256 + tid;         // 0 .. 2^20
    int t = g & 63;
    long wbase = ((long)(g >> 6) << 10) + (t << 2);   // wave: 4KB contiguous
    const float* wp = pW + wbase;
    float4 a0 = *(const float4*)(wp);         // dense 1KB
    float4 a1 = *(const float4*)(wp + 256);
    float4 a2 = *(const float4*)(wp + 512);
    float4 a3 = *(const float4*)(wp + 768);
    unsigned short* wq = wB + wbase;
    uint2 p0, p1, p2, p3;
    p0.x = pk2(a0.x, a0.y); p0.y = pk2(a0.z, a0.w);
    p1.x = pk2(a1.x, a1.y); p1.y = pk2(a1.z, a1.w);
    p2.x = pk2(a2.x, a2.y); p2.y = pk2(a2.z, a2.w);
    p3.x = pk2(a3.x, a3.y); p3.y = pk2(a3.z, a3.w);
    *(uint2*)(wq) = p0;                       // 8B stores, wave-dense 512B
    *(uint2*)(wq + 256) = p1;
    *(uint2*)(wq + 512) = p2;
    *(uint2*)(wq + 768) = p3;
  }
}

// m97-recipe GEMM (R8-exact): C[2048][4096] = S * W^T (both bf16, K
// contiguous), epilogue sigmoid(acc + pb[n]) -> fp32.
// 128x128 block tile, BK=64, 4 waves in 2x2, each wave 4x4 of 16x16x32 MFMA.
// LDS [row][64] ushorts with XOR 16B-chunk swizzle (phys = kc ^ (row&7)),
// filled by global_load_lds with the swizzle pre-applied to the per-lane
// GLOBAL source address (m173 pattern). Fragment reads: 0 bank conflicts.
// 32 KiB LDS, grid 512 -> 2 blocks/CU anti-phase cover.
#define BM 128
#define BN 128
#define BK 64

__global__ __launch_bounds__(256) void gemm_kernel(
    const unsigned short* __restrict__ S, const unsigned short* __restrict__ W,
    const float* __restrict__ pb, float* __restrict__ out) {
  __shared__ unsigned short As[BM * BK];   // unpadded (global_load_lds)
  __shared__ unsigned short Bs[BN * BK];
  int tid = threadIdx.x;
  int lane = tid & 63;
  int wave = tid >> 6;

  // T1 XCD swizzle (neutral at L3-fit, kept from benched R8 artifact)
  int orig = blockIdx.x;                     // 0..511
  int wg = ((orig & 7) << 6) + (orig >> 3);
  int n0 = (wg & 31) * BN;                   // 32 n-tiles
  int r0 = (wg >> 5) * BM;                   // 16 m-tiles
  int wr = wave >> 1, wc = wave & 1;

  int srow = (wave << 5) + (lane >> 3);            // + i*8 per issue
  int scol = (((lane & 7) ^ (lane >> 3)) << 3);    // swizzled k-element offset
  const unsigned short* gA = S + (long)(r0 + srow) * KD + scol;
  const unsigned short* gB = W + (long)(n0 + srow) * KD + scol;
  unsigned short* lA = &As[(wave << 5) * BK];  // wave-uniform base; HW adds lane*16B
  unsigned short* lB = &Bs[(wave << 5) * BK];

  f32x4 acc[4][4] = {};

  for (int kt = 0; kt < KD; kt += BK) {
    __syncthreads();
#pragma unroll
    for (int i = 0; i < 4; ++i) {
      __builtin_amdgcn_global_load_lds(
          (const __attribute__((address_space(1))) unsigned int*)(gA + (long)i * 8 * KD + kt),
          (__attribute__((address_space(3))) unsigned int*)(lA + i * 8 * BK), 16, 0, 0);
      __builtin_amdgcn_global_load_lds(
          (const __attribute__((address_space(1))) unsigned int*)(gB + (long)i * 8 * KD + kt),
          (__attribute__((address_space(3))) unsigned int*)(lB + i * 8 * BK), 16, 0, 0);
    }
    __syncthreads();
#pragma unroll
    for (int ks = 0; ks < 2; ++ks) {
      // fragment chunk kc_lin = ks*4 + (lane>>4); physical chunk =
      // kc_lin ^ (row & 7); row&7 == lane&7 for all t (t*16 is 0 mod 8).
      int swz = (((ks << 2) + (lane >> 4)) ^ (lane & 7)) << 3;
      bf16x8 af[4], bfr[4];
#pragma unroll
      for (int t = 0; t < 4; ++t) {
        af[t]  = *(const bf16x8*)&As[((wr << 6) + t * 16 + (lane & 15)) * BK + swz];
        bfr[t] = *(const bf16x8*)&Bs[((wc << 6) + t * 16 + (lane & 15)) * BK + swz];
      }
#pragma unroll
      for (int mt = 0; mt < 4; ++mt)
#pragma unroll
        for (int nt = 0; nt < 4; ++nt)
          acc[mt][nt] = __builtin_amdgcn_mfma_f32_16x16x32_bf16(af[mt], bfr[nt], acc[mt][nt], 0, 0, 0);
    }
  }

  // epilogue: C/D layout col=lane&15, row=(lane>>4)*4+i  [m89/m91]
#pragma unroll
  for (int nt = 0; nt < 4; ++nt) {
    int col = n0 + (wc << 6) + nt * 16 + (lane & 15);
    float pbv = pb[col];
#pragma unroll
    for (int mt = 0; mt < 4; ++mt) {
      int row = r0 + (wr << 6) + mt * 16 + ((lane >> 4) << 2);
#pragma unroll
      for (int i = 0; i < 4; ++i) {
        float v = acc[mt][nt][i] + pbv;
        out[(long)(row + i) * ND + col] = 1.0f / (1.0f + __expf(-v));
      }
    }
  }
}

extern "C" void kernel_launch(void* const* d_in, const int* in_sizes, int n_in,
                              void* d_out, int out_size, void* d_ws, size_t ws_size,
                              hipStream_t stream) {
  const float* x  = (const float*)d_in[0];   // (2048, 4, 4096)
  const float* lW = (const float*)d_in[1];   // (8, 4)
  const float* lb = (const float*)d_in[2];   // (8,)
  const float* pW = (const float*)d_in[3];   // (4096, 4096)
  const float* pb = (const float*)d_in[4];   // (4096,)
  float* out = (float*)d_out;                // (2048, 4096) fp32

  unsigned short* sB = (unsigned short*)d_ws;          // 2048*4096 bf16 = 16 MiB
  unsigned short* wB = sB + (long)MD * KD;             // 4096*4096 bf16 = 32 MiB

  prep_kernel<<<8192, 256, 0, stream>>>(x, lW, lb, pW, sB, wB);
  gemm_kernel<<<512, 256, 0, stream>>>(sB, wB, pb, out);
}